// Round 1
// baseline (481.596 us; speedup 1.0000x reference)
//
#include <hip/hip_runtime.h>
#include <math.h>

// ---------------------------------------------------------------------------
// 3-layer GCN forward.
// Pipeline per call (deterministic, graph-capture safe):
//   1. deg count (int atomics over edge dst)
//   2. exclusive scan -> rowptr + cursor   (single block, chunked)
//   3. dinv[i] = rsqrt(deg[i]+1)           (+1 = self loop)
//   4. CSR fill (scatter src ids by dst)
//   5. per layer: GEMM (h = X@W, scaled by dinv[row]) then gather-aggregate:
//        out[c] = act( dinv[c] * (sum_{r->c} hs[r] + hs[c]) + b )
// ---------------------------------------------------------------------------

__global__ void count_kernel(const int* __restrict__ col, int* __restrict__ deg, int E) {
    int e = blockIdx.x * blockDim.x + threadIdx.x;
    if (e < E) atomicAdd(&deg[col[e]], 1);
}

__global__ void scan_kernel(const int* __restrict__ deg, int* __restrict__ rowptr,
                            int* __restrict__ cursor, int n) {
    __shared__ int buf[1024];
    __shared__ int carry;
    const int t = threadIdx.x;
    if (t == 0) carry = 0;
    __syncthreads();
    for (int base = 0; base < n; base += 1024) {
        int i = base + t;
        int v = (i < n) ? deg[i] : 0;
        buf[t] = v;
        __syncthreads();
        for (int off = 1; off < 1024; off <<= 1) {
            int add = (t >= off) ? buf[t - off] : 0;
            __syncthreads();
            buf[t] += add;
            __syncthreads();
        }
        int excl = buf[t] - v;          // exclusive prefix within chunk
        if (i < n) {
            int val = carry + excl;
            rowptr[i] = val;
            cursor[i] = val;
        }
        int total = buf[1023];
        __syncthreads();
        if (t == 0) carry += total;
        __syncthreads();
    }
    if (t == 0) rowptr[n] = carry;
}

__global__ void dinv_kernel(const int* __restrict__ deg, float* __restrict__ dinv, int n) {
    int i = blockIdx.x * blockDim.x + threadIdx.x;
    if (i < n) dinv[i] = rsqrtf((float)deg[i] + 1.0f);
}

__global__ void fill_kernel(const int* __restrict__ row, const int* __restrict__ col,
                            int* __restrict__ cursor, int* __restrict__ csr, int E) {
    int e = blockIdx.x * blockDim.x + threadIdx.x;
    if (e < E) {
        int c = col[e];
        int pos = atomicAdd(&cursor[c], 1);
        csr[pos] = row[e];
    }
}

// h = X @ W, then scale row r by dinv[r].  X is [n,128], W is [128,OUT].
// W staged in LDS; X read directly (broadcast within wave, L1-resident).
template <int OUT>
__global__ __launch_bounds__(256) void gemm_kernel(const float* __restrict__ X,
                                                   const float* __restrict__ W,
                                                   const float* __restrict__ dinv,
                                                   float* __restrict__ out, int n) {
    __shared__ float Wl[128 * OUT];
    const int t = threadIdx.x;
    for (int i = t; i < 128 * OUT; i += 256) Wl[i] = W[i];
    __syncthreads();

    constexpr int CQ  = OUT / 4;   // column quads per row
    constexpr int RPI = 256 / CQ;  // rows per block-iteration
    const int cq = t % CQ;
    const int rl = t / CQ;
    const float4* X4 = (const float4*)X;

    for (int row0 = blockIdx.x * RPI; row0 < n; row0 += gridDim.x * RPI) {
        const int row = row0 + rl;
        if (row < n) {
            float4 acc = {0.f, 0.f, 0.f, 0.f};
            const float4* xrow = X4 + (size_t)row * 32;  // 128 floats = 32 float4
#pragma unroll 8
            for (int k4 = 0; k4 < 32; ++k4) {
                float4 xv = xrow[k4];
                const float* wp = &Wl[k4 * 4 * OUT + cq * 4];
                float4 w0 = *(const float4*)(wp);
                float4 w1 = *(const float4*)(wp + OUT);
                float4 w2 = *(const float4*)(wp + 2 * OUT);
                float4 w3 = *(const float4*)(wp + 3 * OUT);
                acc.x = fmaf(xv.x, w0.x, acc.x);
                acc.x = fmaf(xv.y, w1.x, acc.x);
                acc.x = fmaf(xv.z, w2.x, acc.x);
                acc.x = fmaf(xv.w, w3.x, acc.x);
                acc.y = fmaf(xv.x, w0.y, acc.y);
                acc.y = fmaf(xv.y, w1.y, acc.y);
                acc.y = fmaf(xv.z, w2.y, acc.y);
                acc.y = fmaf(xv.w, w3.y, acc.y);
                acc.z = fmaf(xv.x, w0.z, acc.z);
                acc.z = fmaf(xv.y, w1.z, acc.z);
                acc.z = fmaf(xv.z, w2.z, acc.z);
                acc.z = fmaf(xv.w, w3.z, acc.z);
                acc.w = fmaf(xv.x, w0.w, acc.w);
                acc.w = fmaf(xv.y, w1.w, acc.w);
                acc.w = fmaf(xv.z, w2.w, acc.w);
                acc.w = fmaf(xv.w, w3.w, acc.w);
            }
            const float s = dinv[row];
            acc.x *= s; acc.y *= s; acc.z *= s; acc.w *= s;
            *(float4*)&out[(size_t)row * OUT + cq * 4] = acc;
        }
    }
}

// out[c] = act( dinv[c] * (sum_{r in in(c)} hs[r] + hs[c]) + bias )
template <int F, bool RELU>
__global__ __launch_bounds__(256) void agg_kernel(const float* __restrict__ hs,
                                                  const int* __restrict__ rowptr,
                                                  const int* __restrict__ csr,
                                                  const float* __restrict__ dinv,
                                                  const float* __restrict__ bias,
                                                  float* __restrict__ out, int n) {
    constexpr int LPN = F / 2;     // lanes per node (float2 per lane)
    constexpr int NPB = 256 / LPN; // nodes per block
    const int t = threadIdx.x;
    const int node = blockIdx.x * NPB + t / LPN;
    const int fi = (t % LPN) * 2;
    if (node >= n) return;

    float2 acc = *(const float2*)&hs[(size_t)node * F + fi];  // self loop
    const int s = rowptr[node];
    const int e = rowptr[node + 1];
    for (int i = s; i < e; ++i) {
        int r = csr[i];
        float2 v = *(const float2*)&hs[(size_t)r * F + fi];
        acc.x += v.x;
        acc.y += v.y;
    }
    const float dc = dinv[node];
    const float2 b = *(const float2*)&bias[fi];
    float ox = fmaf(acc.x, dc, b.x);
    float oy = fmaf(acc.y, dc, b.y);
    if (RELU) {
        ox = fmaxf(ox, 0.f);
        oy = fmaxf(oy, 0.f);
    }
    float2 res = {ox, oy};
    *(float2*)&out[(size_t)node * F + fi] = res;
}

extern "C" void kernel_launch(void* const* d_in, const int* in_sizes, int n_in,
                              void* d_out, int out_size, void* d_ws, size_t ws_size,
                              hipStream_t stream) {
    const float* x  = (const float*)d_in[0];
    const int*   ei = (const int*)d_in[1];
    // d_in[2] = batch (unused in eval forward)
    const float* W1 = (const float*)d_in[3];
    const float* b1 = (const float*)d_in[4];
    const float* W2 = (const float*)d_in[5];
    const float* b2 = (const float*)d_in[6];
    const float* W3 = (const float*)d_in[7];
    const float* b3 = (const float*)d_in[8];
    float* out = (float*)d_out;

    const int N = in_sizes[0] / 128;
    const int E = in_sizes[1] / 2;
    const int* erow = ei;       // sources
    const int* ecol = ei + E;   // destinations

    char* ws = (char*)d_ws;
    auto alloc = [&](size_t bytes) {
        char* p = ws;
        ws += (bytes + 255) & ~(size_t)255;
        return p;
    };
    int*   deg    = (int*)alloc((size_t)N * 4);
    int*   rowptr = (int*)alloc((size_t)(N + 1) * 4);
    int*   cursor = (int*)alloc((size_t)N * 4);
    int*   csr    = (int*)alloc((size_t)E * 4);
    float* dinv   = (float*)alloc((size_t)N * 4);
    float* buf1   = (float*)alloc((size_t)N * 128 * 4);
    float* buf2   = (float*)alloc((size_t)N * 128 * 4);

    hipMemsetAsync(deg, 0, (size_t)N * 4, stream);
    count_kernel<<<(E + 255) / 256, 256, 0, stream>>>(ecol, deg, E);
    scan_kernel<<<1, 1024, 0, stream>>>(deg, rowptr, cursor, N);
    dinv_kernel<<<(N + 255) / 256, 256, 0, stream>>>(deg, dinv, N);
    fill_kernel<<<(E + 255) / 256, 256, 0, stream>>>(erow, ecol, cursor, csr, E);

    // Layer 1: h = relu(prop(x @ W1) + b1)
    gemm_kernel<128><<<512, 256, 0, stream>>>(x, W1, dinv, buf1, N);
    agg_kernel<128, true><<<(N + 3) / 4, 256, 0, stream>>>(buf1, rowptr, csr, dinv, b1, buf2, N);

    // Layer 2
    gemm_kernel<128><<<512, 256, 0, stream>>>(buf2, W2, dinv, buf1, N);
    agg_kernel<128, true><<<(N + 3) / 4, 256, 0, stream>>>(buf1, rowptr, csr, dinv, b2, buf2, N);

    // Layer 3: logits (no relu), 32 classes -> d_out
    gemm_kernel<32><<<512, 256, 0, stream>>>(buf2, W3, dinv, buf1, N);
    agg_kernel<32, false><<<(N + 15) / 16, 256, 0, stream>>>(buf1, rowptr, csr, dinv, b3, out, N);
}

// Round 3
// 396.967 us; speedup vs baseline: 1.2132x; 1.2132x over previous
//
#include <hip/hip_runtime.h>
#include <math.h>

// ---------------------------------------------------------------------------
// 3-layer GCN forward.
// Pipeline per call (deterministic, graph-capture safe):
//   1. deg count (int atomics over edge dst)
//   2. two-level exclusive scan -> rowptr + cursor (+ fused dinv)
//      (scan temporaries alias buf1, which is dead until the first GEMM)
//   3. CSR fill (scatter src ids by dst)
//   4. per layer: GEMM (h = X@W, scaled by dinv[row]) then gather-aggregate:
//        out[c] = act( dinv[c] * (sum_{r->c} hs[r] + hs[c]) + b )
// ---------------------------------------------------------------------------

__global__ void count_kernel(const int* __restrict__ col, int* __restrict__ deg, int E, int n) {
    int e = blockIdx.x * blockDim.x + threadIdx.x;
    if (e < E) {
        int c = col[e];
        if ((unsigned)c < (unsigned)n) atomicAdd(&deg[c], 1);
    }
}

// Phase 1: each block scans a 1024-element chunk (256 threads x 4 elems).
__global__ __launch_bounds__(256) void scan1_kernel(const int* __restrict__ deg,
                                                    int* __restrict__ local,
                                                    int* __restrict__ blocksums, int n) {
    __shared__ int wsum[4];
    const int t = threadIdx.x;
    const int lane = t & 63;
    const int wv = t >> 6;
    const int base = blockIdx.x * 1024 + t * 4;
    int a0 = (base + 0 < n) ? deg[base + 0] : 0;
    int a1 = (base + 1 < n) ? deg[base + 1] : 0;
    int a2 = (base + 2 < n) ? deg[base + 2] : 0;
    int a3 = (base + 3 < n) ? deg[base + 3] : 0;
    const int tot = a0 + a1 + a2 + a3;
    int incl = tot;
#pragma unroll
    for (int off = 1; off < 64; off <<= 1) {
        int u = __shfl_up(incl, off);
        if (lane >= off) incl += u;
    }
    if (lane == 63) wsum[wv] = incl;
    __syncthreads();
    int woff = 0;
#pragma unroll
    for (int w = 0; w < 4; ++w) woff += (w < wv) ? wsum[w] : 0;
    const int excl = woff + incl - tot;
    if (base + 0 < n) local[base + 0] = excl;
    if (base + 1 < n) local[base + 1] = excl + a0;
    if (base + 2 < n) local[base + 2] = excl + a0 + a1;
    if (base + 3 < n) local[base + 3] = excl + a0 + a1 + a2;
    if (t == 255) blocksums[blockIdx.x] = woff + incl;  // block total
}

// Phase 2: one wave scans block totals (nb <= 64) -> exclusive offsets + grand total.
__global__ void scan2_kernel(const int* __restrict__ blocksums, int* __restrict__ blockoff,
                             int* __restrict__ rowptr, int nb, int n) {
    const int lane = threadIdx.x;  // launched with 64 threads
    int v = (lane < nb) ? blocksums[lane] : 0;
    int incl = v;
#pragma unroll
    for (int off = 1; off < 64; off <<= 1) {
        int u = __shfl_up(incl, off);
        if (lane >= off) incl += u;
    }
    if (lane < nb) blockoff[lane] = incl - v;   // exclusive block offset
    if (lane == 63) rowptr[n] = incl;           // grand total
}

// Phase 3: combine + write rowptr/cursor; fused dinv = rsqrt(deg+1).
__global__ void scan3_kernel(const int* __restrict__ local, const int* __restrict__ blockoff,
                             const int* __restrict__ deg, int* __restrict__ rowptr,
                             int* __restrict__ cursor, float* __restrict__ dinv, int n) {
    int i = blockIdx.x * blockDim.x + threadIdx.x;
    if (i < n) {
        const int v = local[i] + blockoff[i >> 10];
        rowptr[i] = v;
        cursor[i] = v;
        dinv[i] = rsqrtf((float)deg[i] + 1.0f);
    }
}

__global__ void fill_kernel(const int* __restrict__ row, const int* __restrict__ col,
                            int* __restrict__ cursor, int* __restrict__ csr, int E, int n) {
    int e = blockIdx.x * blockDim.x + threadIdx.x;
    if (e < E) {
        int c = col[e];
        int r = row[e];
        if ((unsigned)c < (unsigned)n && (unsigned)r < (unsigned)n) {
            int pos = atomicAdd(&cursor[c], 1);
            csr[pos] = r;
        }
    }
}

// h = X @ W, then scale row r by dinv[r].  X is [n,128], W is [128,OUT].
// W staged in LDS; X read directly (broadcast within wave, L1-resident).
template <int OUT>
__global__ __launch_bounds__(256) void gemm_kernel(const float* __restrict__ X,
                                                   const float* __restrict__ W,
                                                   const float* __restrict__ dinv,
                                                   float* __restrict__ out, int n) {
    __shared__ float Wl[128 * OUT];
    const int t = threadIdx.x;
    for (int i = t; i < 128 * OUT; i += 256) Wl[i] = W[i];
    __syncthreads();

    constexpr int CQ  = OUT / 4;   // column quads per row
    constexpr int RPI = 256 / CQ;  // rows per block-iteration
    const int cq = t % CQ;
    const int rl = t / CQ;
    const float4* X4 = (const float4*)X;

    for (int row0 = blockIdx.x * RPI; row0 < n; row0 += gridDim.x * RPI) {
        const int row = row0 + rl;
        if (row < n) {
            float4 acc = {0.f, 0.f, 0.f, 0.f};
            const float4* xrow = X4 + (size_t)row * 32;  // 128 floats = 32 float4
#pragma unroll 8
            for (int k4 = 0; k4 < 32; ++k4) {
                float4 xv = xrow[k4];
                const float* wp = &Wl[k4 * 4 * OUT + cq * 4];
                float4 w0 = *(const float4*)(wp);
                float4 w1 = *(const float4*)(wp + OUT);
                float4 w2 = *(const float4*)(wp + 2 * OUT);
                float4 w3 = *(const float4*)(wp + 3 * OUT);
                acc.x = fmaf(xv.x, w0.x, acc.x);
                acc.x = fmaf(xv.y, w1.x, acc.x);
                acc.x = fmaf(xv.z, w2.x, acc.x);
                acc.x = fmaf(xv.w, w3.x, acc.x);
                acc.y = fmaf(xv.x, w0.y, acc.y);
                acc.y = fmaf(xv.y, w1.y, acc.y);
                acc.y = fmaf(xv.z, w2.y, acc.y);
                acc.y = fmaf(xv.w, w3.y, acc.y);
                acc.z = fmaf(xv.x, w0.z, acc.z);
                acc.z = fmaf(xv.y, w1.z, acc.z);
                acc.z = fmaf(xv.z, w2.z, acc.z);
                acc.z = fmaf(xv.w, w3.z, acc.z);
                acc.w = fmaf(xv.x, w0.w, acc.w);
                acc.w = fmaf(xv.y, w1.w, acc.w);
                acc.w = fmaf(xv.z, w2.w, acc.w);
                acc.w = fmaf(xv.w, w3.w, acc.w);
            }
            const float s = dinv[row];
            acc.x *= s; acc.y *= s; acc.z *= s; acc.w *= s;
            *(float4*)&out[(size_t)row * OUT + cq * 4] = acc;
        }
    }
}

// out[c] = act( dinv[c] * (sum_{r in in(c)} hs[r] + hs[c]) + bias )
template <int F, bool RELU>
__global__ __launch_bounds__(256) void agg_kernel(const float* __restrict__ hs,
                                                  const int* __restrict__ rowptr,
                                                  const int* __restrict__ csr,
                                                  const float* __restrict__ dinv,
                                                  const float* __restrict__ bias,
                                                  float* __restrict__ out, int n) {
    constexpr int LPN = F / 2;     // lanes per node (float2 per lane)
    constexpr int NPB = 256 / LPN; // nodes per block
    const int t = threadIdx.x;
    const int node = blockIdx.x * NPB + t / LPN;
    const int fi = (t % LPN) * 2;
    if (node >= n) return;

    float2 acc = *(const float2*)&hs[(size_t)node * F + fi];  // self loop
    const int s = rowptr[node];
    const int e = rowptr[node + 1];
    for (int i = s; i < e; ++i) {
        int r = csr[i];
        float2 v = *(const float2*)&hs[(size_t)r * F + fi];
        acc.x += v.x;
        acc.y += v.y;
    }
    const float dc = dinv[node];
    const float2 b = *(const float2*)&bias[fi];
    float ox = fmaf(acc.x, dc, b.x);
    float oy = fmaf(acc.y, dc, b.y);
    if (RELU) {
        ox = fmaxf(ox, 0.f);
        oy = fmaxf(oy, 0.f);
    }
    float2 res = {ox, oy};
    *(float2*)&out[(size_t)node * F + fi] = res;
}

extern "C" void kernel_launch(void* const* d_in, const int* in_sizes, int n_in,
                              void* d_out, int out_size, void* d_ws, size_t ws_size,
                              hipStream_t stream) {
    const float* x  = (const float*)d_in[0];
    const int*   ei = (const int*)d_in[1];
    // d_in[2] = batch (unused in eval forward)
    const float* W1 = (const float*)d_in[3];
    const float* b1 = (const float*)d_in[4];
    const float* W2 = (const float*)d_in[5];
    const float* b2 = (const float*)d_in[6];
    const float* W3 = (const float*)d_in[7];
    const float* b3 = (const float*)d_in[8];
    float* out = (float*)d_out;

    const int N = in_sizes[0] / 128;
    const int E = in_sizes[1] / 2;
    const int* erow = ei;       // sources
    const int* ecol = ei + E;   // destinations

    // Workspace layout — EXACTLY the round-1-proven footprint (55,200,768 B).
    char* ws = (char*)d_ws;
    auto alloc = [&](size_t bytes) {
        char* p = ws;
        ws += (bytes + 255) & ~(size_t)255;
        return p;
    };
    int*   deg    = (int*)alloc((size_t)N * 4);
    int*   rowptr = (int*)alloc((size_t)(N + 1) * 4);
    int*   cursor = (int*)alloc((size_t)N * 4);
    int*   csr    = (int*)alloc((size_t)E * 4);
    float* dinv   = (float*)alloc((size_t)N * 4);
    float* buf1   = (float*)alloc((size_t)N * 128 * 4);
    float* buf2   = (float*)alloc((size_t)N * 128 * 4);

    // Scan temporaries alias buf1: buf1 is written only by the first GEMM,
    // which launches strictly after scan3 has consumed them.
    int* local = (int*)buf1;           // N ints
    int* bsums = local + N;            // 64 ints
    int* boffs = bsums + 64;           // 64 ints

    const int nb = (N + 1023) / 1024;  // 49 for N=50000 (scan2 assumes nb <= 64)

    hipMemsetAsync(deg, 0, (size_t)N * 4, stream);
    count_kernel<<<(E + 255) / 256, 256, 0, stream>>>(ecol, deg, E, N);
    scan1_kernel<<<nb, 256, 0, stream>>>(deg, local, bsums, N);
    scan2_kernel<<<1, 64, 0, stream>>>(bsums, boffs, rowptr, nb, N);
    scan3_kernel<<<(N + 255) / 256, 256, 0, stream>>>(local, boffs, deg, rowptr, cursor, dinv, N);
    fill_kernel<<<(E + 255) / 256, 256, 0, stream>>>(erow, ecol, cursor, csr, E, N);

    // Layer 1: h = relu(prop(x @ W1) + b1)
    gemm_kernel<128><<<512, 256, 0, stream>>>(x, W1, dinv, buf1, N);
    agg_kernel<128, true><<<(N + 3) / 4, 256, 0, stream>>>(buf1, rowptr, csr, dinv, b1, buf2, N);

    // Layer 2
    gemm_kernel<128><<<512, 256, 0, stream>>>(buf2, W2, dinv, buf1, N);
    agg_kernel<128, true><<<(N + 3) / 4, 256, 0, stream>>>(buf1, rowptr, csr, dinv, b2, buf2, N);

    // Layer 3: logits (no relu), 32 classes -> d_out
    gemm_kernel<32><<<512, 256, 0, stream>>>(buf2, W3, dinv, buf1, N);
    agg_kernel<32, false><<<(N + 15) / 16, 256, 0, stream>>>(buf1, rowptr, csr, dinv, b3, out, N);
}

// Round 4
// 319.815 us; speedup vs baseline: 1.5059x; 1.2412x over previous
//
#include <hip/hip_runtime.h>
#include <math.h>

// ---------------------------------------------------------------------------
// 3-layer GCN forward.
// Pipeline per call (deterministic, graph-capture safe):
//   1. deg count (int atomics over edge dst)
//   2. two-level exclusive scan -> rowptr + cursor (+ fused dinv)
//      (scan temporaries alias buf1, which is dead until the first GEMM)
//   3. CSR fill (scatter src ids by dst)
//   4. per layer: GEMM (h = X@W, scaled by dinv[row]) then gather-aggregate:
//        out[c] = act( dinv[c] * (sum_{r->c} hs[r] + hs[c]) + b )
// ---------------------------------------------------------------------------

__global__ void count_kernel(const int* __restrict__ col, int* __restrict__ deg, int E, int n) {
    int e = blockIdx.x * blockDim.x + threadIdx.x;
    if (e < E) {
        int c = col[e];
        if ((unsigned)c < (unsigned)n) atomicAdd(&deg[c], 1);
    }
}

// Phase 1: each block scans a 1024-element chunk (256 threads x 4 elems).
__global__ __launch_bounds__(256) void scan1_kernel(const int* __restrict__ deg,
                                                    int* __restrict__ local,
                                                    int* __restrict__ blocksums, int n) {
    __shared__ int wsum[4];
    const int t = threadIdx.x;
    const int lane = t & 63;
    const int wv = t >> 6;
    const int base = blockIdx.x * 1024 + t * 4;
    int a0 = (base + 0 < n) ? deg[base + 0] : 0;
    int a1 = (base + 1 < n) ? deg[base + 1] : 0;
    int a2 = (base + 2 < n) ? deg[base + 2] : 0;
    int a3 = (base + 3 < n) ? deg[base + 3] : 0;
    const int tot = a0 + a1 + a2 + a3;
    int incl = tot;
#pragma unroll
    for (int off = 1; off < 64; off <<= 1) {
        int u = __shfl_up(incl, off);
        if (lane >= off) incl += u;
    }
    if (lane == 63) wsum[wv] = incl;
    __syncthreads();
    int woff = 0;
#pragma unroll
    for (int w = 0; w < 4; ++w) woff += (w < wv) ? wsum[w] : 0;
    const int excl = woff + incl - tot;
    if (base + 0 < n) local[base + 0] = excl;
    if (base + 1 < n) local[base + 1] = excl + a0;
    if (base + 2 < n) local[base + 2] = excl + a0 + a1;
    if (base + 3 < n) local[base + 3] = excl + a0 + a1 + a2;
    if (t == 255) blocksums[blockIdx.x] = woff + incl;  // block total
}

// Phase 2: one wave scans block totals (nb <= 64) -> exclusive offsets + grand total.
__global__ void scan2_kernel(const int* __restrict__ blocksums, int* __restrict__ blockoff,
                             int* __restrict__ rowptr, int nb, int n) {
    const int lane = threadIdx.x;  // launched with 64 threads
    int v = (lane < nb) ? blocksums[lane] : 0;
    int incl = v;
#pragma unroll
    for (int off = 1; off < 64; off <<= 1) {
        int u = __shfl_up(incl, off);
        if (lane >= off) incl += u;
    }
    if (lane < nb) blockoff[lane] = incl - v;   // exclusive block offset
    if (lane == 63) rowptr[n] = incl;           // grand total
}

// Phase 3: combine + write rowptr/cursor; fused dinv = rsqrt(deg+1).
__global__ void scan3_kernel(const int* __restrict__ local, const int* __restrict__ blockoff,
                             const int* __restrict__ deg, int* __restrict__ rowptr,
                             int* __restrict__ cursor, float* __restrict__ dinv, int n) {
    int i = blockIdx.x * blockDim.x + threadIdx.x;
    if (i < n) {
        const int v = local[i] + blockoff[i >> 10];
        rowptr[i] = v;
        cursor[i] = v;
        dinv[i] = rsqrtf((float)deg[i] + 1.0f);
    }
}

__global__ void fill_kernel(const int* __restrict__ row, const int* __restrict__ col,
                            int* __restrict__ cursor, int* __restrict__ csr, int E, int n) {
    int e = blockIdx.x * blockDim.x + threadIdx.x;
    if (e < E) {
        int c = col[e];
        int r = row[e];
        if ((unsigned)c < (unsigned)n && (unsigned)r < (unsigned)n) {
            int pos = atomicAdd(&cursor[c], 1);
            csr[pos] = r;
        }
    }
}

// h = X @ W, then scale row r by dinv[r].  X is [n,128], W is [128,OUT].
// W staged in LDS; each thread register-blocks R=4 rows x one column-quad so
// 16 LDS floats feed 64 FMAs (was 16).  X row chunks are lane-uniform within
// a column-group -> L1 broadcast.
template <int OUT>
__global__ __launch_bounds__(256) void gemm_kernel(const float* __restrict__ X,
                                                   const float* __restrict__ W,
                                                   const float* __restrict__ dinv,
                                                   float* __restrict__ out, int n) {
    __shared__ float Wl[128 * OUT];
    const int t = threadIdx.x;
    for (int i = t; i < 128 * OUT; i += 256) Wl[i] = W[i];
    __syncthreads();

    constexpr int CQ  = OUT / 4;        // column quads (32 or 8)
    constexpr int RG  = 256 / CQ;       // row-groups per block (8 or 32)
    constexpr int R   = 4;              // rows per thread
    constexpr int RPI = RG * R;         // rows per block-iteration (32 or 128)
    const int cq = t % CQ;
    const int rg = t / CQ;
    const float4* X4 = (const float4*)X;

    for (int base = blockIdx.x * RPI; base < n; base += gridDim.x * RPI) {
        const int r0 = base + rg * R;
        float4 acc[R];
#pragma unroll
        for (int r = 0; r < R; ++r) acc[r] = make_float4(0.f, 0.f, 0.f, 0.f);

        if (r0 + R <= n) {
#pragma unroll 4
            for (int k4 = 0; k4 < 32; ++k4) {
                const float* wp = &Wl[k4 * 4 * OUT + cq * 4];
                float4 w0 = *(const float4*)(wp);
                float4 w1 = *(const float4*)(wp + OUT);
                float4 w2 = *(const float4*)(wp + 2 * OUT);
                float4 w3 = *(const float4*)(wp + 3 * OUT);
#pragma unroll
                for (int r = 0; r < R; ++r) {
                    float4 xv = X4[(size_t)(r0 + r) * 32 + k4];
                    acc[r].x = fmaf(xv.x, w0.x, acc[r].x);
                    acc[r].x = fmaf(xv.y, w1.x, acc[r].x);
                    acc[r].x = fmaf(xv.z, w2.x, acc[r].x);
                    acc[r].x = fmaf(xv.w, w3.x, acc[r].x);
                    acc[r].y = fmaf(xv.x, w0.y, acc[r].y);
                    acc[r].y = fmaf(xv.y, w1.y, acc[r].y);
                    acc[r].y = fmaf(xv.z, w2.y, acc[r].y);
                    acc[r].y = fmaf(xv.w, w3.y, acc[r].y);
                    acc[r].z = fmaf(xv.x, w0.z, acc[r].z);
                    acc[r].z = fmaf(xv.y, w1.z, acc[r].z);
                    acc[r].z = fmaf(xv.z, w2.z, acc[r].z);
                    acc[r].z = fmaf(xv.w, w3.z, acc[r].z);
                    acc[r].w = fmaf(xv.x, w0.w, acc[r].w);
                    acc[r].w = fmaf(xv.y, w1.w, acc[r].w);
                    acc[r].w = fmaf(xv.z, w2.w, acc[r].w);
                    acc[r].w = fmaf(xv.w, w3.w, acc[r].w);
                }
            }
#pragma unroll
            for (int r = 0; r < R; ++r) {
                const float s = dinv[r0 + r];
                acc[r].x *= s; acc[r].y *= s; acc[r].z *= s; acc[r].w *= s;
                *(float4*)&out[(size_t)(r0 + r) * OUT + cq * 4] = acc[r];
            }
        } else if (r0 < n) {
            for (int r = 0; r < R; ++r) {
                const int row = r0 + r;
                if (row >= n) break;
                float4 a = make_float4(0.f, 0.f, 0.f, 0.f);
                for (int k4 = 0; k4 < 32; ++k4) {
                    float4 xv = X4[(size_t)row * 32 + k4];
                    const float* wp = &Wl[k4 * 4 * OUT + cq * 4];
                    float4 w0 = *(const float4*)(wp);
                    float4 w1 = *(const float4*)(wp + OUT);
                    float4 w2 = *(const float4*)(wp + 2 * OUT);
                    float4 w3 = *(const float4*)(wp + 3 * OUT);
                    a.x = fmaf(xv.x, w0.x, a.x); a.x = fmaf(xv.y, w1.x, a.x);
                    a.x = fmaf(xv.z, w2.x, a.x); a.x = fmaf(xv.w, w3.x, a.x);
                    a.y = fmaf(xv.x, w0.y, a.y); a.y = fmaf(xv.y, w1.y, a.y);
                    a.y = fmaf(xv.z, w2.y, a.y); a.y = fmaf(xv.w, w3.y, a.y);
                    a.z = fmaf(xv.x, w0.z, a.z); a.z = fmaf(xv.y, w1.z, a.z);
                    a.z = fmaf(xv.z, w2.z, a.z); a.z = fmaf(xv.w, w3.z, a.z);
                    a.w = fmaf(xv.x, w0.w, a.w); a.w = fmaf(xv.y, w1.w, a.w);
                    a.w = fmaf(xv.z, w2.w, a.w); a.w = fmaf(xv.w, w3.w, a.w);
                }
                const float s = dinv[row];
                a.x *= s; a.y *= s; a.z *= s; a.w *= s;
                *(float4*)&out[(size_t)row * OUT + cq * 4] = a;
            }
        }
    }
}

// out[c] = act( dinv[c] * (sum_{r in in(c)} hs[r] + hs[c]) + bias )
// 4x unrolled neighbor loop: 4 independent index loads + 4 independent
// gathers + 4 accumulators per iteration -> ~4x memory-level parallelism.
template <int F, bool RELU>
__global__ __launch_bounds__(256) void agg_kernel(const float* __restrict__ hs,
                                                  const int* __restrict__ rowptr,
                                                  const int* __restrict__ csr,
                                                  const float* __restrict__ dinv,
                                                  const float* __restrict__ bias,
                                                  float* __restrict__ out, int n) {
    constexpr int LPN = F / 2;     // lanes per node (float2 per lane)
    constexpr int NPB = 256 / LPN; // nodes per block
    constexpr int F2  = F / 2;
    const int t = threadIdx.x;
    const int node = blockIdx.x * NPB + t / LPN;
    const int fo = t % LPN;        // float2 index within row
    if (node >= n) return;

    const float2* h2 = (const float2*)hs;
    float2 a0 = h2[(size_t)node * F2 + fo];  // self loop
    float2 a1 = {0.f, 0.f}, a2 = {0.f, 0.f}, a3 = {0.f, 0.f};
    const int s = rowptr[node];
    const int e = rowptr[node + 1];
    int i = s;
    for (; i + 4 <= e; i += 4) {
        const int r0 = csr[i + 0];
        const int r1 = csr[i + 1];
        const int r2 = csr[i + 2];
        const int r3 = csr[i + 3];
        float2 v0 = h2[(size_t)r0 * F2 + fo];
        float2 v1 = h2[(size_t)r1 * F2 + fo];
        float2 v2 = h2[(size_t)r2 * F2 + fo];
        float2 v3 = h2[(size_t)r3 * F2 + fo];
        a0.x += v0.x; a0.y += v0.y;
        a1.x += v1.x; a1.y += v1.y;
        a2.x += v2.x; a2.y += v2.y;
        a3.x += v3.x; a3.y += v3.y;
    }
    for (; i < e; ++i) {
        const int r = csr[i];
        float2 v = h2[(size_t)r * F2 + fo];
        a0.x += v.x; a0.y += v.y;
    }
    const float accx = (a0.x + a1.x) + (a2.x + a3.x);
    const float accy = (a0.y + a1.y) + (a2.y + a3.y);
    const float dc = dinv[node];
    const float2 b = *(const float2*)&bias[fo * 2];
    float ox = fmaf(accx, dc, b.x);
    float oy = fmaf(accy, dc, b.y);
    if (RELU) {
        ox = fmaxf(ox, 0.f);
        oy = fmaxf(oy, 0.f);
    }
    float2 res = {ox, oy};
    *(float2*)&out[(size_t)node * F + fo * 2] = res;
}

extern "C" void kernel_launch(void* const* d_in, const int* in_sizes, int n_in,
                              void* d_out, int out_size, void* d_ws, size_t ws_size,
                              hipStream_t stream) {
    const float* x  = (const float*)d_in[0];
    const int*   ei = (const int*)d_in[1];
    // d_in[2] = batch (unused in eval forward)
    const float* W1 = (const float*)d_in[3];
    const float* b1 = (const float*)d_in[4];
    const float* W2 = (const float*)d_in[5];
    const float* b2 = (const float*)d_in[6];
    const float* W3 = (const float*)d_in[7];
    const float* b3 = (const float*)d_in[8];
    float* out = (float*)d_out;

    const int N = in_sizes[0] / 128;
    const int E = in_sizes[1] / 2;
    const int* erow = ei;       // sources
    const int* ecol = ei + E;   // destinations

    // Workspace layout — EXACTLY the round-1-proven footprint (55,200,768 B).
    char* ws = (char*)d_ws;
    auto alloc = [&](size_t bytes) {
        char* p = ws;
        ws += (bytes + 255) & ~(size_t)255;
        return p;
    };
    int*   deg    = (int*)alloc((size_t)N * 4);
    int*   rowptr = (int*)alloc((size_t)(N + 1) * 4);
    int*   cursor = (int*)alloc((size_t)N * 4);
    int*   csr    = (int*)alloc((size_t)E * 4);
    float* dinv   = (float*)alloc((size_t)N * 4);
    float* buf1   = (float*)alloc((size_t)N * 128 * 4);
    float* buf2   = (float*)alloc((size_t)N * 128 * 4);

    // Scan temporaries alias buf1: buf1 is written only by the first GEMM,
    // which launches strictly after scan3 has consumed them.
    int* local = (int*)buf1;           // N ints
    int* bsums = local + N;            // 64 ints
    int* boffs = bsums + 64;           // 64 ints

    const int nb = (N + 1023) / 1024;  // 49 for N=50000 (scan2 assumes nb <= 64)

    hipMemsetAsync(deg, 0, (size_t)N * 4, stream);
    count_kernel<<<(E + 255) / 256, 256, 0, stream>>>(ecol, deg, E, N);
    scan1_kernel<<<nb, 256, 0, stream>>>(deg, local, bsums, N);
    scan2_kernel<<<1, 64, 0, stream>>>(bsums, boffs, rowptr, nb, N);
    scan3_kernel<<<(N + 255) / 256, 256, 0, stream>>>(local, boffs, deg, rowptr, cursor, dinv, N);
    fill_kernel<<<(E + 255) / 256, 256, 0, stream>>>(erow, ecol, cursor, csr, E, N);

    // Layer 1: h = relu(prop(x @ W1) + b1)
    gemm_kernel<128><<<512, 256, 0, stream>>>(x, W1, dinv, buf1, N);
    agg_kernel<128, true><<<(N + 3) / 4, 256, 0, stream>>>(buf1, rowptr, csr, dinv, b1, buf2, N);

    // Layer 2
    gemm_kernel<128><<<512, 256, 0, stream>>>(buf2, W2, dinv, buf1, N);
    agg_kernel<128, true><<<(N + 3) / 4, 256, 0, stream>>>(buf1, rowptr, csr, dinv, b2, buf2, N);

    // Layer 3: logits (no relu), 32 classes -> d_out
    gemm_kernel<32><<<512, 256, 0, stream>>>(buf2, W3, dinv, buf1, N);
    agg_kernel<32, false><<<(N + 15) / 16, 256, 0, stream>>>(buf1, rowptr, csr, dinv, b3, out, N);
}